// Round 1
// baseline (277.142 us; speedup 1.0000x reference)
//
#include <hip/hip_runtime.h>
#include <hip/hip_bf16.h>
#include <stdint.h>

typedef unsigned short u16;
typedef __attribute__((ext_vector_type(4))) float f32x4;
typedef __attribute__((ext_vector_type(8))) short s16x8;
typedef __attribute__((ext_vector_type(4))) float fvec4;

#define NH 12
#define DH 64
#define HID 768
#define SEQ 197
#define SP 208            // padded seq rows for Q/K slabs
#define VP 224            // padded seq cols for Vt slab
#define NREL 732
#define BATCH 64
#define MROWS (BATCH*SEQ) // 12608
#define NCAT (3*HID)      // 2304

static __device__ __forceinline__ u16 f2bf(float f) {
  union { float f; uint32_t u; } v; v.f = f;
  uint32_t u = v.u;
  return (u16)((u + 0x7FFFu + ((u >> 16) & 1u)) >> 16);
}

// ---------------- prep: hidden fp32 -> bf16 ----------------
__global__ __launch_bounds__(256) void conv_x(const float* __restrict__ x, u16* __restrict__ xb, int n8) {
  int i = blockIdx.x * 256 + threadIdx.x;
  if (i >= n8) return;
  fvec4 a = ((const fvec4*)x)[2 * i];
  fvec4 b = ((const fvec4*)x)[2 * i + 1];
  s16x8 r;
  r[0] = (short)f2bf(a[0]); r[1] = (short)f2bf(a[1]); r[2] = (short)f2bf(a[2]); r[3] = (short)f2bf(a[3]);
  r[4] = (short)f2bf(b[0]); r[5] = (short)f2bf(b[1]); r[6] = (short)f2bf(b[2]); r[7] = (short)f2bf(b[3]);
  ((s16x8*)xb)[i] = r;
}

// ---------------- prep: W's -> transposed concat bf16 [NCAT][HID] ----------------
__global__ __launch_bounds__(256) void conv_w(const float* __restrict__ Wq, const float* __restrict__ Wk,
                                              const float* __restrict__ Wv, u16* __restrict__ Wt) {
  __shared__ float t[64][65];
  int n0 = blockIdx.x * 64;  // output row block (0..2303)
  int k0 = blockIdx.y * 64;  // k block (0..767)
  int m = n0 / HID;
  const float* W = (m == 0) ? Wq : ((m == 1) ? Wk : Wv);
  int nn0 = n0 - m * HID;
  for (int i = threadIdx.x; i < 64 * 64; i += 256) {
    int r = i >> 6, c = i & 63;
    t[r][c] = W[(size_t)(k0 + r) * HID + nn0 + c];   // coalesced read
  }
  __syncthreads();
  for (int i = threadIdx.x; i < 64 * 64; i += 256) {
    int r = i >> 6, c = i & 63;
    Wt[(size_t)(n0 + r) * HID + k0 + c] = f2bf(t[c][r]);  // coalesced write
  }
}

// ---------------- prep: bias concat (bq, 0, bv) ----------------
__global__ __launch_bounds__(256) void conv_b(const float* __restrict__ bq, const float* __restrict__ bv,
                                              float* __restrict__ bc) {
  int i = blockIdx.x * 256 + threadIdx.x;
  if (i < NCAT) {
    int m = i / HID, r = i - m * HID;
    bc[i] = (m == 0) ? bq[r] : ((m == 2) ? bv[r] : 0.f);
  }
}

// ---------------- fused QKV GEMM: [12608x768]x[768x2304], bf16 MFMA ----------------
// C row -> (b,s); col -> (m,h,d). Writes Q (scaled 1/8) / K as [bh][s][d], V transposed [bh][d][s].
__global__ __launch_bounds__(256) void qkv_gemm(const u16* __restrict__ Xb, const u16* __restrict__ Wt,
                                                const float* __restrict__ bc, u16* __restrict__ Qw,
                                                u16* __restrict__ Kw, u16* __restrict__ Vtw) {
  __shared__ u16 As[128 * 64];
  __shared__ u16 Bs[128 * 64];
  const int tid = threadIdx.x;
  const int w = tid >> 6, l = tid & 63;
  const int mt = blockIdx.x, nt = blockIdx.y;
  const int wr = w >> 1, wc = w & 1;
  const int lg = l >> 4, li = l & 15;
  const int srow = tid >> 3, scol = tid & 7;

  f32x4 acc[4][4] = {};

  for (int kt = 0; kt < 12; ++kt) {
    const int k0 = kt * 64;
    __syncthreads();
#pragma unroll
    for (int i = 0; i < 4; ++i) {
      int r = i * 32 + srow;
      int grow = mt * 128 + r; if (grow >= MROWS) grow = MROWS - 1;  // clamp (pad rows never stored)
      s16x8 va = *(const s16x8*)(Xb + (size_t)grow * HID + k0 + scol * 8);
      int byteoff = (r * 128 + scol * 16) ^ ((r & 7) << 4);          // XOR bank swizzle
      *(s16x8*)((char*)As + byteoff) = va;
      int nrow = nt * 128 + r;
      s16x8 vb = *(const s16x8*)(Wt + (size_t)nrow * HID + k0 + scol * 8);
      *(s16x8*)((char*)Bs + byteoff) = vb;
    }
    __syncthreads();
#pragma unroll
    for (int kk = 0; kk < 2; ++kk) {
      s16x8 af[4], bf[4];
#pragma unroll
      for (int mi = 0; mi < 4; ++mi) {
        int r = wr * 64 + mi * 16 + li;
        int byteoff = (r * 128 + kk * 64 + lg * 16) ^ ((r & 7) << 4);
        af[mi] = *(const s16x8*)((const char*)As + byteoff);
      }
#pragma unroll
      for (int ni = 0; ni < 4; ++ni) {
        int r = wc * 64 + ni * 16 + li;
        int byteoff = (r * 128 + kk * 64 + lg * 16) ^ ((r & 7) << 4);
        bf[ni] = *(const s16x8*)((const char*)Bs + byteoff);
      }
#pragma unroll
      for (int mi = 0; mi < 4; ++mi)
#pragma unroll
        for (int ni = 0; ni < 4; ++ni)
          acc[mi][ni] = __builtin_amdgcn_mfma_f32_16x16x32_bf16(af[mi], bf[ni], acc[mi][ni], 0, 0, 0);
    }
  }

  // epilogue: bias, q-scale, scatter to Q/K/Vt
#pragma unroll
  for (int mi = 0; mi < 4; ++mi) {
#pragma unroll
    for (int j = 0; j < 4; ++j) {
      int row = mt * 128 + wr * 64 + mi * 16 + lg * 4 + j;
      if (row < MROWS) {
        int b = row / SEQ, s = row - b * SEQ;
#pragma unroll
        for (int ni = 0; ni < 4; ++ni) {
          int col = nt * 128 + wc * 64 + ni * 16 + li;
          float vv = acc[mi][ni][j] + bc[col];
          int m = col / HID;
          int c7 = col - m * HID;
          int h = c7 >> 6, d = c7 & 63;
          int bh = b * NH + h;
          if (m == 0)      Qw[((size_t)bh * SP + s) * DH + d] = f2bf(vv * 0.125f);
          else if (m == 1) Kw[((size_t)bh * SP + s) * DH + d] = f2bf(vv);
          else             Vtw[((size_t)bh * DH + d) * VP + s] = f2bf(vv);
        }
      }
    }
  }
}

// ---------------- fused attention: 1 block per (b,h) ----------------
__global__ __launch_bounds__(256) void attn(const u16* __restrict__ Qw, const u16* __restrict__ Kw,
                                            const u16* __restrict__ Vtw, const float* __restrict__ bias_table,
                                            float* __restrict__ out) {
  __shared__ float btab[NREL];
  __shared__ u16 P[4][16 * 232];   // per-wave P transpose buffer (232 pad: conflict-free b128)
  const int tid = threadIdx.x;
  const int w = tid >> 6, l = tid & 63;
  const int bh = blockIdx.x;
  const int b = bh / NH, h = bh - b * NH;
  const int lg = l >> 4, li = l & 15;

  for (int i = tid; i < NREL; i += 256) btab[i] = bias_table[(size_t)i * NH + h];
  for (int i = tid; i < 4 * 16 * 232; i += 256) ((u16*)P)[i] = 0;
  __syncthreads();

  const u16* Qb = Qw + (size_t)bh * SP * DH;
  const u16* Kb = Kw + (size_t)bh * SP * DH;
  const u16* Vb = Vtw + (size_t)bh * DH * VP;

  for (int it = 0; it < 4; ++it) {
    const int qf = it * 4 + w;        // 0..15, 13 valid — uniform loop for barriers
    const bool valid = (qf < 13);
    float rinv[4];

    if (valid) {
      s16x8 a0 = *(const s16x8*)(Qb + (size_t)(qf * 16 + li) * DH + lg * 8);
      s16x8 a1 = *(const s16x8*)(Qb + (size_t)(qf * 16 + li) * DH + 32 + lg * 8);
      f32x4 S[13];
#pragma unroll
      for (int kf = 0; kf < 13; ++kf) {
        s16x8 b0 = *(const s16x8*)(Kb + (size_t)(kf * 16 + li) * DH + lg * 8);
        s16x8 b1 = *(const s16x8*)(Kb + (size_t)(kf * 16 + li) * DH + 32 + lg * 8);
        f32x4 c = {};
        c = __builtin_amdgcn_mfma_f32_16x16x32_bf16(a0, b0, c, 0, 0, 0);
        c = __builtin_amdgcn_mfma_f32_16x16x32_bf16(a1, b1, c, 0, 0, 0);
        S[kf] = c;
      }
      // relative-position bias + mask
      int qv[4], iq[4], jq[4];
#pragma unroll
      for (int j = 0; j < 4; ++j) {
        int q = qf * 16 + lg * 4 + j; qv[j] = q;
        int p = q - 1;
        iq[j] = p / 14; jq[j] = p - iq[j] * 14;
      }
#pragma unroll
      for (int kf = 0; kf < 13; ++kf) {
        int k = kf * 16 + li;
        int pk = k - 1;
        int ik = pk / 14, jk = pk - ik * 14;
        bool kval = (k < SEQ);
#pragma unroll
        for (int j = 0; j < 4; ++j) {
          int idx;
          if (qv[j] == 0) idx = (k == 0) ? 731 : 729;
          else if (k == 0) idx = 730;
          else idx = (iq[j] - ik + 13) * 27 + (jq[j] - jk + 13);
          idx = (idx < 0) ? 0 : ((idx > 731) ? 731 : idx);   // clamp (garbage rows/cols only)
          float sv = S[kf][j] + btab[idx];
          S[kf][j] = kval ? sv : -__builtin_inff();
        }
      }
      // softmax over 13 regs x 16 lanes (per 16-lane group)
#pragma unroll
      for (int j = 0; j < 4; ++j) {
        float m = -__builtin_inff();
#pragma unroll
        for (int kf = 0; kf < 13; ++kf) m = fmaxf(m, S[kf][j]);
        m = fmaxf(m, __shfl_xor(m, 1));
        m = fmaxf(m, __shfl_xor(m, 2));
        m = fmaxf(m, __shfl_xor(m, 4));
        m = fmaxf(m, __shfl_xor(m, 8));
        float sum = 0.f;
#pragma unroll
        for (int kf = 0; kf < 13; ++kf) {
          float p = __expf(S[kf][j] - m);
          S[kf][j] = p;
          sum += p;
        }
        sum += __shfl_xor(sum, 1);
        sum += __shfl_xor(sum, 2);
        sum += __shfl_xor(sum, 4);
        sum += __shfl_xor(sum, 8);
        rinv[j] = 1.0f / sum;
      }
      // transpose P into LDS (bf16)
#pragma unroll
      for (int kf = 0; kf < 13; ++kf)
#pragma unroll
        for (int j = 0; j < 4; ++j)
          P[w][(lg * 4 + j) * 232 + kf * 16 + li] = f2bf(S[kf][j]);
    }
    __syncthreads();
    if (valid) {
#pragma unroll
      for (int nf = 0; nf < 4; ++nf) {
        f32x4 c = {};
#pragma unroll
        for (int t = 0; t < 7; ++t) {
          s16x8 pa = *(const s16x8*)(&P[w][li * 232 + t * 32 + lg * 8]);
          s16x8 vb = *(const s16x8*)(Vb + (size_t)(nf * 16 + li) * VP + t * 32 + lg * 8);
          c = __builtin_amdgcn_mfma_f32_16x16x32_bf16(pa, vb, c, 0, 0, 0);
        }
#pragma unroll
        for (int j = 0; j < 4; ++j) {
          int q = qf * 16 + lg * 4 + j;
          if (q < SEQ)
            out[((size_t)(b * SEQ + q)) * HID + h * DH + nf * 16 + li] = c[j] * rinv[j];
        }
      }
    }
    __syncthreads();
  }
}

extern "C" void kernel_launch(void* const* d_in, const int* in_sizes, int n_in,
                              void* d_out, int out_size, void* d_ws, size_t ws_size,
                              hipStream_t stream) {
  const float* hidden = (const float*)d_in[0];
  const float* Wq = (const float*)d_in[1];
  const float* bq = (const float*)d_in[2];
  const float* Wk = (const float*)d_in[3];
  const float* Wv = (const float*)d_in[4];
  const float* bv = (const float*)d_in[5];
  const float* btab = (const float*)d_in[6];
  float* out = (float*)d_out;

  char* ws = (char*)d_ws;
  u16* Xb  = (u16*)(ws);                       // 12608*768*2      = 19,365,888
  u16* Wt  = (u16*)(ws + 19365888);            // 2304*768*2       =  3,538,944
  float* bc = (float*)(ws + 22904832);         // 2304*4           =      9,216
  u16* Qw  = (u16*)(ws + 22914048);            // 768*208*64*2     = 20,447,232
  u16* Kw  = (u16*)(ws + 43361280);            // 768*208*64*2     = 20,447,232
  u16* Vtw = (u16*)(ws + 63808512);            // 768*64*224*2     = 22,020,096 (end 85,828,608)

  conv_x<<<dim3(4728), dim3(256), 0, stream>>>(hidden, Xb, (MROWS * HID) / 8);
  conv_w<<<dim3(NCAT / 64, HID / 64), dim3(256), 0, stream>>>(Wq, Wk, Wv, Wt);
  conv_b<<<dim3(9), dim3(256), 0, stream>>>(bq, bv, bc);
  qkv_gemm<<<dim3(99, 18), dim3(256), 0, stream>>>(Xb, Wt, bc, Qw, Kw, Vtw);
  attn<<<dim3(768), dim3(256), 0, stream>>>(Qw, Kw, Vtw, btab, out);
}

// Round 2
// 249.421 us; speedup vs baseline: 1.1111x; 1.1111x over previous
//
#include <hip/hip_runtime.h>
#include <hip/hip_bf16.h>
#include <stdint.h>

typedef unsigned short u16;
typedef __attribute__((ext_vector_type(4))) float f32x4;
typedef __attribute__((ext_vector_type(8))) short s16x8;
typedef __attribute__((ext_vector_type(4))) float fvec4;

#define NH 12
#define DH 64
#define HID 768
#define SEQ 197
#define SP 208            // padded seq rows for Q/K slabs
#define VP 224            // padded seq cols for Vt slab
#define NREL 732
#define BATCH 64
#define MROWS (BATCH*SEQ) // 12608
#define NCAT (3*HID)      // 2304

static __device__ __forceinline__ u16 f2bf(float f) {
  union { float f; uint32_t u; } v; v.f = f;
  uint32_t u = v.u;
  return (u16)((u + 0x7FFFu + ((u >> 16) & 1u)) >> 16);
}

// ---------------- prep: hidden fp32 -> bf16 ----------------
__global__ __launch_bounds__(256) void conv_x(const float* __restrict__ x, u16* __restrict__ xb, int n8) {
  int i = blockIdx.x * 256 + threadIdx.x;
  if (i >= n8) return;
  fvec4 a = ((const fvec4*)x)[2 * i];
  fvec4 b = ((const fvec4*)x)[2 * i + 1];
  s16x8 r;
  r[0] = (short)f2bf(a[0]); r[1] = (short)f2bf(a[1]); r[2] = (short)f2bf(a[2]); r[3] = (short)f2bf(a[3]);
  r[4] = (short)f2bf(b[0]); r[5] = (short)f2bf(b[1]); r[6] = (short)f2bf(b[2]); r[7] = (short)f2bf(b[3]);
  ((s16x8*)xb)[i] = r;
}

// ---------------- prep: W's -> transposed concat bf16 [NCAT][HID] ----------------
__global__ __launch_bounds__(256) void conv_w(const float* __restrict__ Wq, const float* __restrict__ Wk,
                                              const float* __restrict__ Wv, u16* __restrict__ Wt) {
  __shared__ float t[64][65];
  int n0 = blockIdx.x * 64;  // output row block (0..2303)
  int k0 = blockIdx.y * 64;  // k block (0..767)
  int m = n0 / HID;
  const float* W = (m == 0) ? Wq : ((m == 1) ? Wk : Wv);
  int nn0 = n0 - m * HID;
  for (int i = threadIdx.x; i < 64 * 64; i += 256) {
    int r = i >> 6, c = i & 63;
    t[r][c] = W[(size_t)(k0 + r) * HID + nn0 + c];   // coalesced read
  }
  __syncthreads();
  for (int i = threadIdx.x; i < 64 * 64; i += 256) {
    int r = i >> 6, c = i & 63;
    Wt[(size_t)(n0 + r) * HID + k0 + c] = f2bf(t[c][r]);  // coalesced write
  }
}

// ---------------- prep: bias concat (bq, 0, bv) ----------------
__global__ __launch_bounds__(256) void conv_b(const float* __restrict__ bq, const float* __restrict__ bv,
                                              float* __restrict__ bc) {
  int i = blockIdx.x * 256 + threadIdx.x;
  if (i < NCAT) {
    int m = i / HID, r = i - m * HID;
    bc[i] = (m == 0) ? bq[r] : ((m == 2) ? bv[r] : 0.f);
  }
}

// ---------------- fused QKV GEMM: [12608x768]x[768x2304], bf16 MFMA ----------------
// 256x256 tile, BK=64, 8 waves (2x4), 2-phase pipelined global_load_lds staging.
// LDS layout: [256][64] bf16 linear rows; 16B chunk c of row r stored at physical
// chunk c^(r&7) (achieved by inverse-swizzling the GLOBAL source address, since
// global_load_lds writes linearly: base + lane*16). ds_read applies same XOR.

#define BK 64

// stage one 256x64 bf16 tile; wave w stages chunks w*4+i (1KB each = 8 rows)
static __device__ __forceinline__ void stage_tile(const u16* __restrict__ gbase, int grow0, int growmax,
                                                  u16* lds, int w, int l) {
#pragma unroll
  for (int i = 0; i < 4; ++i) {
    int ch = w * 4 + i;                    // wave-uniform
    int r = ch * 8 + (l >> 3);
    int grow = grow0 + r; if (grow > growmax) grow = growmax;
    int c = (l & 7) ^ (l >> 3);            // inverse swizzle on source
    const u16* g = gbase + (size_t)grow * HID + c * 8;
    __builtin_amdgcn_global_load_lds((const __attribute__((address_space(1))) void*)g,
                                     (__attribute__((address_space(3))) void*)(lds + ch * 512),
                                     16, 0, 0);
  }
}

static __device__ __forceinline__ void compute_tile(const u16* As, const u16* Bs, int wm, int wn,
                                                    int li, int lg, f32x4 acc[8][4]) {
#pragma unroll
  for (int kk = 0; kk < 2; ++kk) {
    s16x8 af[8], bf[4];
#pragma unroll
    for (int mi = 0; mi < 8; ++mi) {
      int r = wm * 128 + mi * 16 + li;
      int c = (kk * 4 + lg) ^ (r & 7);
      af[mi] = *(const s16x8*)((const char*)As + r * 128 + c * 16);
    }
#pragma unroll
    for (int ni = 0; ni < 4; ++ni) {
      int r = wn * 64 + ni * 16 + li;
      int c = (kk * 4 + lg) ^ (r & 7);
      bf[ni] = *(const s16x8*)((const char*)Bs + r * 128 + c * 16);
    }
#pragma unroll
    for (int mi = 0; mi < 8; ++mi)
#pragma unroll
      for (int ni = 0; ni < 4; ++ni)
        acc[mi][ni] = __builtin_amdgcn_mfma_f32_16x16x32_bf16(af[mi], bf[ni], acc[mi][ni], 0, 0, 0);
  }
}

__global__ __launch_bounds__(512, 2) void qkv_gemm(const u16* __restrict__ Xb, const u16* __restrict__ Wt,
                                                   const float* __restrict__ bc, u16* __restrict__ Qw,
                                                   u16* __restrict__ Kw, u16* __restrict__ Vtw) {
  __shared__ u16 As0[256 * BK], As1[256 * BK];
  __shared__ u16 Bs0[256 * BK], Bs1[256 * BK];
  const int tid = threadIdx.x;
  const int w = tid >> 6, l = tid & 63;
  const int mt = blockIdx.x, nt = blockIdx.y;
  const int wm = w >> 2, wn = w & 3;        // 2x4 wave grid
  const int lg = l >> 4, li = l & 15;
  const int arow0 = mt * 256, brow0 = nt * 256;

  f32x4 acc[8][4] = {};

  stage_tile(Xb, arow0, MROWS - 1, As0, w, l);
  stage_tile(Wt, brow0, NCAT - 1, Bs0, w, l);
  __syncthreads();                          // drain vmcnt, all waves see tile 0

  for (int kt2 = 0; kt2 < 6; ++kt2) {
    const int kt = kt2 * 2;
    // prefetch tile kt+1 into buffer 1, then compute tile kt from buffer 0
    stage_tile(Xb + (kt + 1) * BK, arow0, MROWS - 1, As1, w, l);
    stage_tile(Wt + (kt + 1) * BK, brow0, NCAT - 1, Bs1, w, l);
    compute_tile(As0, Bs0, wm, wn, li, lg, acc);
    __syncthreads();
    // prefetch tile kt+2 into buffer 0, then compute tile kt+1 from buffer 1
    if (kt + 2 < 12) {
      stage_tile(Xb + (kt + 2) * BK, arow0, MROWS - 1, As0, w, l);
      stage_tile(Wt + (kt + 2) * BK, brow0, NCAT - 1, Bs0, w, l);
    }
    compute_tile(As1, Bs1, wm, wn, li, lg, acc);
    __syncthreads();
  }

  // epilogue: bias, q-scale, scatter to Q/K/Vt. Per-ni column block lies in one
  // (m,h) — wave-uniform branch, no divergence.
  int mv[4], hv[4], dv0[4]; float bcv[4];
#pragma unroll
  for (int ni = 0; ni < 4; ++ni) {
    int col = brow0 + wn * 64 + ni * 16 + li;
    int m = col / HID;
    int c7 = col - m * HID;
    mv[ni] = m; hv[ni] = c7 >> 6; dv0[ni] = c7 & 63;
    bcv[ni] = bc[col];
  }
#pragma unroll
  for (int mi = 0; mi < 8; ++mi) {
#pragma unroll
    for (int j = 0; j < 4; ++j) {
      int row = arow0 + wm * 128 + mi * 16 + lg * 4 + j;
      if (row < MROWS) {
        int b = row / SEQ, s = row - b * SEQ;
#pragma unroll
        for (int ni = 0; ni < 4; ++ni) {
          float vv = acc[mi][ni][j] + bcv[ni];
          int bh = b * NH + hv[ni];
          if (mv[ni] == 0)      Qw[((size_t)bh * SP + s) * DH + dv0[ni]] = f2bf(vv * 0.125f);
          else if (mv[ni] == 1) Kw[((size_t)bh * SP + s) * DH + dv0[ni]] = f2bf(vv);
          else                  Vtw[((size_t)bh * DH + dv0[ni]) * VP + s] = f2bf(vv);
        }
      }
    }
  }
}

// ---------------- fused attention: 1 block per (b,h) ----------------
__global__ __launch_bounds__(256) void attn(const u16* __restrict__ Qw, const u16* __restrict__ Kw,
                                            const u16* __restrict__ Vtw, const float* __restrict__ bias_table,
                                            float* __restrict__ out) {
  __shared__ float btab[NREL];
  __shared__ u16 P[4][16 * 232];   // per-wave P transpose buffer (232 pad: conflict-free b128)
  const int tid = threadIdx.x;
  const int w = tid >> 6, l = tid & 63;
  const int bh = blockIdx.x;
  const int b = bh / NH, h = bh - b * NH;
  const int lg = l >> 4, li = l & 15;

  for (int i = tid; i < NREL; i += 256) btab[i] = bias_table[(size_t)i * NH + h];
  for (int i = tid; i < 4 * 16 * 232; i += 256) ((u16*)P)[i] = 0;
  __syncthreads();

  const u16* Qb = Qw + (size_t)bh * SP * DH;
  const u16* Kb = Kw + (size_t)bh * SP * DH;
  const u16* Vb = Vtw + (size_t)bh * DH * VP;

  for (int it = 0; it < 4; ++it) {
    const int qf = it * 4 + w;        // 0..15, 13 valid — uniform loop for barriers
    const bool valid = (qf < 13);
    float rinv[4];

    if (valid) {
      s16x8 a0 = *(const s16x8*)(Qb + (size_t)(qf * 16 + li) * DH + lg * 8);
      s16x8 a1 = *(const s16x8*)(Qb + (size_t)(qf * 16 + li) * DH + 32 + lg * 8);
      f32x4 S[13];
#pragma unroll
      for (int kf = 0; kf < 13; ++kf) {
        s16x8 b0 = *(const s16x8*)(Kb + (size_t)(kf * 16 + li) * DH + lg * 8);
        s16x8 b1 = *(const s16x8*)(Kb + (size_t)(kf * 16 + li) * DH + 32 + lg * 8);
        f32x4 c = {};
        c = __builtin_amdgcn_mfma_f32_16x16x32_bf16(a0, b0, c, 0, 0, 0);
        c = __builtin_amdgcn_mfma_f32_16x16x32_bf16(a1, b1, c, 0, 0, 0);
        S[kf] = c;
      }
      // relative-position bias + mask
      int qv[4], iq[4], jq[4];
#pragma unroll
      for (int j = 0; j < 4; ++j) {
        int q = qf * 16 + lg * 4 + j; qv[j] = q;
        int p = q - 1;
        iq[j] = p / 14; jq[j] = p - iq[j] * 14;
      }
#pragma unroll
      for (int kf = 0; kf < 13; ++kf) {
        int k = kf * 16 + li;
        int pk = k - 1;
        int ik = pk / 14, jk = pk - ik * 14;
        bool kval = (k < SEQ);
#pragma unroll
        for (int j = 0; j < 4; ++j) {
          int idx;
          if (qv[j] == 0) idx = (k == 0) ? 731 : 729;
          else if (k == 0) idx = 730;
          else idx = (iq[j] - ik + 13) * 27 + (jq[j] - jk + 13);
          idx = (idx < 0) ? 0 : ((idx > 731) ? 731 : idx);   // clamp (garbage rows/cols only)
          float sv = S[kf][j] + btab[idx];
          S[kf][j] = kval ? sv : -__builtin_inff();
        }
      }
      // softmax over 13 regs x 16 lanes (per 16-lane group)
#pragma unroll
      for (int j = 0; j < 4; ++j) {
        float m = -__builtin_inff();
#pragma unroll
        for (int kf = 0; kf < 13; ++kf) m = fmaxf(m, S[kf][j]);
        m = fmaxf(m, __shfl_xor(m, 1));
        m = fmaxf(m, __shfl_xor(m, 2));
        m = fmaxf(m, __shfl_xor(m, 4));
        m = fmaxf(m, __shfl_xor(m, 8));
        float sum = 0.f;
#pragma unroll
        for (int kf = 0; kf < 13; ++kf) {
          float p = __expf(S[kf][j] - m);
          S[kf][j] = p;
          sum += p;
        }
        sum += __shfl_xor(sum, 1);
        sum += __shfl_xor(sum, 2);
        sum += __shfl_xor(sum, 4);
        sum += __shfl_xor(sum, 8);
        rinv[j] = 1.0f / sum;
      }
      // transpose P into LDS (bf16)
#pragma unroll
      for (int kf = 0; kf < 13; ++kf)
#pragma unroll
        for (int j = 0; j < 4; ++j)
          P[w][(lg * 4 + j) * 232 + kf * 16 + li] = f2bf(S[kf][j]);
    }
    __syncthreads();
    if (valid) {
#pragma unroll
      for (int nf = 0; nf < 4; ++nf) {
        f32x4 c = {};
#pragma unroll
        for (int t = 0; t < 7; ++t) {
          s16x8 pa = *(const s16x8*)(&P[w][li * 232 + t * 32 + lg * 8]);
          s16x8 vb = *(const s16x8*)(Vb + (size_t)(nf * 16 + li) * VP + t * 32 + lg * 8);
          c = __builtin_amdgcn_mfma_f32_16x16x32_bf16(pa, vb, c, 0, 0, 0);
        }
#pragma unroll
        for (int j = 0; j < 4; ++j) {
          int q = qf * 16 + lg * 4 + j;
          if (q < SEQ)
            out[((size_t)(b * SEQ + q)) * HID + h * DH + nf * 16 + li] = c[j] * rinv[j];
        }
      }
    }
    __syncthreads();
  }
}

extern "C" void kernel_launch(void* const* d_in, const int* in_sizes, int n_in,
                              void* d_out, int out_size, void* d_ws, size_t ws_size,
                              hipStream_t stream) {
  const float* hidden = (const float*)d_in[0];
  const float* Wq = (const float*)d_in[1];
  const float* bq = (const float*)d_in[2];
  const float* Wk = (const float*)d_in[3];
  const float* Wv = (const float*)d_in[4];
  const float* bv = (const float*)d_in[5];
  const float* btab = (const float*)d_in[6];
  float* out = (float*)d_out;

  char* ws = (char*)d_ws;
  u16* Xb  = (u16*)(ws);                       // 12608*768*2      = 19,365,888
  u16* Wt  = (u16*)(ws + 19365888);            // 2304*768*2       =  3,538,944
  float* bc = (float*)(ws + 22904832);         // 2304*4           =      9,216
  u16* Qw  = (u16*)(ws + 22914048);            // 768*208*64*2     = 20,447,232
  u16* Kw  = (u16*)(ws + 43361280);            // 768*208*64*2     = 20,447,232
  u16* Vtw = (u16*)(ws + 63808512);            // 768*64*224*2     = 22,020,096 (end 85,828,608)

  conv_x<<<dim3(4728), dim3(256), 0, stream>>>(hidden, Xb, (MROWS * HID) / 8);
  conv_w<<<dim3(NCAT / 64, HID / 64), dim3(256), 0, stream>>>(Wq, Wk, Wv, Wt);
  conv_b<<<dim3(9), dim3(256), 0, stream>>>(bq, bv, bc);
  qkv_gemm<<<dim3(50, 9), dim3(512), 0, stream>>>(Xb, Wt, bc, Qw, Kw, Vtw);
  attn<<<dim3(768), dim3(256), 0, stream>>>(Qw, Kw, Vtw, btab, out);
}

// Round 3
// 216.752 us; speedup vs baseline: 1.2786x; 1.1507x over previous
//
#include <hip/hip_runtime.h>
#include <hip/hip_bf16.h>
#include <stdint.h>

typedef unsigned short u16;
typedef __attribute__((ext_vector_type(4))) float f32x4;
typedef __attribute__((ext_vector_type(8))) short s16x8;
typedef __attribute__((ext_vector_type(4))) float fvec4;

#define NH 12
#define DH 64
#define HID 768
#define SEQ 197
#define SP 208            // padded seq rows for Q/K slabs
#define VP 224            // padded seq cols for Vt slab
#define NREL 732
#define BATCH 64
#define MROWS (BATCH*SEQ) // 12608
#define NCAT (3*HID)      // 2304
#define BK 64
#define MT 99             // grid tiles in M (99*128 = 12672 >= 12608)
#define NT 18             // grid tiles in N (18*128 = 2304)
#define NWG (MT*NT)       // 1782

static __device__ __forceinline__ u16 f2bf(float f) {
  union { float f; uint32_t u; } v; v.f = f;
  uint32_t u = v.u;
  return (u16)((u + 0x7FFFu + ((u >> 16) & 1u)) >> 16);
}

// ---------------- prep: hidden fp32 -> bf16 ----------------
__global__ __launch_bounds__(256) void conv_x(const float* __restrict__ x, u16* __restrict__ xb, int n8) {
  int i = blockIdx.x * 256 + threadIdx.x;
  if (i >= n8) return;
  fvec4 a = ((const fvec4*)x)[2 * i];
  fvec4 b = ((const fvec4*)x)[2 * i + 1];
  s16x8 r;
  r[0] = (short)f2bf(a[0]); r[1] = (short)f2bf(a[1]); r[2] = (short)f2bf(a[2]); r[3] = (short)f2bf(a[3]);
  r[4] = (short)f2bf(b[0]); r[5] = (short)f2bf(b[1]); r[6] = (short)f2bf(b[2]); r[7] = (short)f2bf(b[3]);
  ((s16x8*)xb)[i] = r;
}

// ---------------- prep: W's -> transposed concat bf16 [NCAT][HID] ----------------
__global__ __launch_bounds__(256) void conv_w(const float* __restrict__ Wq, const float* __restrict__ Wk,
                                              const float* __restrict__ Wv, u16* __restrict__ Wt) {
  __shared__ float t[64][65];
  int n0 = blockIdx.x * 64;  // output row block (0..2303)
  int k0 = blockIdx.y * 64;  // k block (0..767)
  int m = n0 / HID;
  const float* W = (m == 0) ? Wq : ((m == 1) ? Wk : Wv);
  int nn0 = n0 - m * HID;
  for (int i = threadIdx.x; i < 64 * 64; i += 256) {
    int r = i >> 6, c = i & 63;
    t[r][c] = W[(size_t)(k0 + r) * HID + nn0 + c];   // coalesced read
  }
  __syncthreads();
  for (int i = threadIdx.x; i < 64 * 64; i += 256) {
    int r = i >> 6, c = i & 63;
    Wt[(size_t)(n0 + r) * HID + k0 + c] = f2bf(t[c][r]);  // coalesced write
  }
}

// ---------------- prep: bias concat (bq, 0, bv) ----------------
__global__ __launch_bounds__(256) void conv_b(const float* __restrict__ bq, const float* __restrict__ bv,
                                              float* __restrict__ bc) {
  int i = blockIdx.x * 256 + threadIdx.x;
  if (i < NCAT) {
    int m = i / HID, r = i - m * HID;
    bc[i] = (m == 0) ? bq[r] : ((m == 2) ? bv[r] : 0.f);
  }
}

// ---------------- fused QKV GEMM: [12608x768]x[768x2304], bf16 MFMA ----------------
// m97-faithful: 128x128 tile, BK=64, 4 waves (2x2), SINGLE 32 KiB LDS buffer,
// 2 barriers/K-step, 3 blocks/CU co-resident for implicit cross-block overlap.
// LDS rows linear; 16B chunk c of row r stored at physical chunk c^(r&7)
// (inverse-swizzled global source; global_load_lds writes linearly).
// XCD-aware bijective swizzle (m204): each XCD owns a contiguous mt band,
// nt-inner => A-band + current B panel stay L2-resident.

// stage one 128x64 bf16 tile; wave w stages 1KB chunks w*4+i (8 rows each)
static __device__ __forceinline__ void stage128(const u16* __restrict__ gbase, int grow0, int growmax,
                                                u16* lds, int w, int l) {
#pragma unroll
  for (int i = 0; i < 4; ++i) {
    int ch = w * 4 + i;                    // wave-uniform 0..15
    int r = ch * 8 + (l >> 3);
    int grow = grow0 + r; if (grow > growmax) grow = growmax;
    int c = (l & 7) ^ (l >> 3);            // inverse swizzle on source
    const u16* g = gbase + (size_t)grow * HID + c * 8;
    __builtin_amdgcn_global_load_lds((const __attribute__((address_space(1))) void*)g,
                                     (__attribute__((address_space(3))) void*)(lds + ch * 512),
                                     16, 0, 0);
  }
}

__global__ __launch_bounds__(256, 3) void qkv_gemm(const u16* __restrict__ Xb, const u16* __restrict__ Wt,
                                                   const float* __restrict__ bc, u16* __restrict__ Qw,
                                                   u16* __restrict__ Kw, u16* __restrict__ Vtw) {
  __shared__ u16 As[128 * BK];
  __shared__ u16 Bs[128 * BK];
  const int tid = threadIdx.x;
  const int w = tid >> 6, l = tid & 63;
  const int wr = w >> 1, wc = w & 1;        // 2x2 wave grid, 64x64 per wave
  const int lg = l >> 4, li = l & 15;

  // bijective XCD chunking (m204): nwg=1782, q=222, r=6
  const int lin = blockIdx.x;
  const int xcd = lin & 7;
  const int pos = lin >> 3;
  const int work = (xcd < 6 ? xcd * 223 : 6 * 223 + (xcd - 6) * 222) + pos;
  const int mt = work / NT, nt = work - mt * NT;
  const int arow0 = mt * 128, brow0 = nt * 128;

  f32x4 acc[4][4] = {};

  for (int kt = 0; kt < 12; ++kt) {
    __syncthreads();                        // previous compute done before overwrite
    stage128(Xb + kt * BK, arow0, MROWS - 1, As, w, l);
    stage128(Wt + kt * BK, brow0, NCAT - 1, Bs, w, l);
    __syncthreads();                        // drain vmcnt; tile visible
#pragma unroll
    for (int kk = 0; kk < 2; ++kk) {
      s16x8 af[4], bf[4];
#pragma unroll
      for (int mi = 0; mi < 4; ++mi) {
        int r = wr * 64 + mi * 16 + li;
        int c = (kk * 4 + lg) ^ (r & 7);
        af[mi] = *(const s16x8*)((const char*)As + r * 128 + c * 16);
      }
#pragma unroll
      for (int ni = 0; ni < 4; ++ni) {
        int r = wc * 64 + ni * 16 + li;
        int c = (kk * 4 + lg) ^ (r & 7);
        bf[ni] = *(const s16x8*)((const char*)Bs + r * 128 + c * 16);
      }
#pragma unroll
      for (int mi = 0; mi < 4; ++mi)
#pragma unroll
        for (int ni = 0; ni < 4; ++ni)
          acc[mi][ni] = __builtin_amdgcn_mfma_f32_16x16x32_bf16(af[mi], bf[ni], acc[mi][ni], 0, 0, 0);
    }
  }

  // epilogue: bias, q-scale, scatter to Q/K/Vt. Per-ni column block lies in one
  // (m,h) — wave-uniform branch (16-col blocks never straddle 64-boundaries).
  int mv[4], hv[4], dv0[4]; float bcv[4];
#pragma unroll
  for (int ni = 0; ni < 4; ++ni) {
    int col = brow0 + wc * 64 + ni * 16 + li;
    int m = col / HID;
    int c7 = col - m * HID;
    mv[ni] = m; hv[ni] = c7 >> 6; dv0[ni] = c7 & 63;
    bcv[ni] = bc[col];
  }
#pragma unroll
  for (int mi = 0; mi < 4; ++mi) {
#pragma unroll
    for (int j = 0; j < 4; ++j) {
      int row = arow0 + wr * 64 + mi * 16 + lg * 4 + j;
      if (row < MROWS) {
        int b = row / SEQ, s = row - b * SEQ;
#pragma unroll
        for (int ni = 0; ni < 4; ++ni) {
          float vv = acc[mi][ni][j] + bcv[ni];
          int bh = b * NH + hv[ni];
          if (mv[ni] == 0)      Qw[((size_t)bh * SP + s) * DH + dv0[ni]] = f2bf(vv * 0.125f);
          else if (mv[ni] == 1) Kw[((size_t)bh * SP + s) * DH + dv0[ni]] = f2bf(vv);
          else                  Vtw[((size_t)bh * DH + dv0[ni]) * VP + s] = f2bf(vv);
        }
      }
    }
  }
}

// ---------------- fused attention: 1 block per (b,h) ----------------
__global__ __launch_bounds__(256) void attn(const u16* __restrict__ Qw, const u16* __restrict__ Kw,
                                            const u16* __restrict__ Vtw, const float* __restrict__ bias_table,
                                            float* __restrict__ out) {
  __shared__ float btab[NREL];
  __shared__ u16 P[4][16 * 232];   // per-wave P transpose buffer (232 pad: conflict-free b128)
  const int tid = threadIdx.x;
  const int w = tid >> 6, l = tid & 63;
  const int bh = blockIdx.x;
  const int b = bh / NH, h = bh - b * NH;
  const int lg = l >> 4, li = l & 15;

  for (int i = tid; i < NREL; i += 256) btab[i] = bias_table[(size_t)i * NH + h];
  for (int i = tid; i < 4 * 16 * 232; i += 256) ((u16*)P)[i] = 0;
  __syncthreads();

  const u16* Qb = Qw + (size_t)bh * SP * DH;
  const u16* Kb = Kw + (size_t)bh * SP * DH;
  const u16* Vb = Vtw + (size_t)bh * DH * VP;

  for (int it = 0; it < 4; ++it) {
    const int qf = it * 4 + w;        // 0..15, 13 valid — uniform loop for barriers
    const bool valid = (qf < 13);
    float rinv[4];

    if (valid) {
      s16x8 a0 = *(const s16x8*)(Qb + (size_t)(qf * 16 + li) * DH + lg * 8);
      s16x8 a1 = *(const s16x8*)(Qb + (size_t)(qf * 16 + li) * DH + 32 + lg * 8);
      f32x4 S[13];
#pragma unroll
      for (int kf = 0; kf < 13; ++kf) {
        s16x8 b0 = *(const s16x8*)(Kb + (size_t)(kf * 16 + li) * DH + lg * 8);
        s16x8 b1 = *(const s16x8*)(Kb + (size_t)(kf * 16 + li) * DH + 32 + lg * 8);
        f32x4 c = {};
        c = __builtin_amdgcn_mfma_f32_16x16x32_bf16(a0, b0, c, 0, 0, 0);
        c = __builtin_amdgcn_mfma_f32_16x16x32_bf16(a1, b1, c, 0, 0, 0);
        S[kf] = c;
      }
      // relative-position bias + mask
      int qv[4], iq[4], jq[4];
#pragma unroll
      for (int j = 0; j < 4; ++j) {
        int q = qf * 16 + lg * 4 + j; qv[j] = q;
        int p = q - 1;
        iq[j] = p / 14; jq[j] = p - iq[j] * 14;
      }
#pragma unroll
      for (int kf = 0; kf < 13; ++kf) {
        int k = kf * 16 + li;
        int pk = k - 1;
        int ik = pk / 14, jk = pk - ik * 14;
        bool kval = (k < SEQ);
#pragma unroll
        for (int j = 0; j < 4; ++j) {
          int idx;
          if (qv[j] == 0) idx = (k == 0) ? 731 : 729;
          else if (k == 0) idx = 730;
          else idx = (iq[j] - ik + 13) * 27 + (jq[j] - jk + 13);
          idx = (idx < 0) ? 0 : ((idx > 731) ? 731 : idx);   // clamp (garbage rows/cols only)
          float sv = S[kf][j] + btab[idx];
          S[kf][j] = kval ? sv : -__builtin_inff();
        }
      }
      // softmax over 13 regs x 16 lanes (per 16-lane group)
#pragma unroll
      for (int j = 0; j < 4; ++j) {
        float m = -__builtin_inff();
#pragma unroll
        for (int kf = 0; kf < 13; ++kf) m = fmaxf(m, S[kf][j]);
        m = fmaxf(m, __shfl_xor(m, 1));
        m = fmaxf(m, __shfl_xor(m, 2));
        m = fmaxf(m, __shfl_xor(m, 4));
        m = fmaxf(m, __shfl_xor(m, 8));
        float sum = 0.f;
#pragma unroll
        for (int kf = 0; kf < 13; ++kf) {
          float p = __expf(S[kf][j] - m);
          S[kf][j] = p;
          sum += p;
        }
        sum += __shfl_xor(sum, 1);
        sum += __shfl_xor(sum, 2);
        sum += __shfl_xor(sum, 4);
        sum += __shfl_xor(sum, 8);
        rinv[j] = 1.0f / sum;
      }
      // transpose P into LDS (bf16)
#pragma unroll
      for (int kf = 0; kf < 13; ++kf)
#pragma unroll
        for (int j = 0; j < 4; ++j)
          P[w][(lg * 4 + j) * 232 + kf * 16 + li] = f2bf(S[kf][j]);
    }
    __syncthreads();
    if (valid) {
#pragma unroll
      for (int nf = 0; nf < 4; ++nf) {
        f32x4 c = {};
#pragma unroll
        for (int t = 0; t < 7; ++t) {
          s16x8 pa = *(const s16x8*)(&P[w][li * 232 + t * 32 + lg * 8]);
          s16x8 vb = *(const s16x8*)(Vb + (size_t)(nf * 16 + li) * VP + t * 32 + lg * 8);
          c = __builtin_amdgcn_mfma_f32_16x16x32_bf16(pa, vb, c, 0, 0, 0);
        }
#pragma unroll
        for (int j = 0; j < 4; ++j) {
          int q = qf * 16 + lg * 4 + j;
          if (q < SEQ)
            out[((size_t)(b * SEQ + q)) * HID + h * DH + nf * 16 + li] = c[j] * rinv[j];
        }
      }
    }
    __syncthreads();
  }
}

extern "C" void kernel_launch(void* const* d_in, const int* in_sizes, int n_in,
                              void* d_out, int out_size, void* d_ws, size_t ws_size,
                              hipStream_t stream) {
  const float* hidden = (const float*)d_in[0];
  const float* Wq = (const float*)d_in[1];
  const float* bq = (const float*)d_in[2];
  const float* Wk = (const float*)d_in[3];
  const float* Wv = (const float*)d_in[4];
  const float* bv = (const float*)d_in[5];
  const float* btab = (const float*)d_in[6];
  float* out = (float*)d_out;

  char* ws = (char*)d_ws;
  u16* Xb  = (u16*)(ws);                       // 12608*768*2      = 19,365,888
  u16* Wt  = (u16*)(ws + 19365888);            // 2304*768*2       =  3,538,944
  float* bc = (float*)(ws + 22904832);         // 2304*4           =      9,216
  u16* Qw  = (u16*)(ws + 22914048);            // 768*208*64*2     = 20,447,232
  u16* Kw  = (u16*)(ws + 43361280);            // 768*208*64*2     = 20,447,232
  u16* Vtw = (u16*)(ws + 63808512);            // 768*64*224*2     = 22,020,096 (end 85,828,608)

  conv_x<<<dim3(4728), dim3(256), 0, stream>>>(hidden, Xb, (MROWS * HID) / 8);
  conv_w<<<dim3(NCAT / 64, HID / 64), dim3(256), 0, stream>>>(Wq, Wk, Wv, Wt);
  conv_b<<<dim3(9), dim3(256), 0, stream>>>(bq, bv, bc);
  qkv_gemm<<<dim3(NWG), dim3(256), 0, stream>>>(Xb, Wt, bc, Qw, Kw, Vtw);
  attn<<<dim3(768), dim3(256), 0, stream>>>(Qw, Kw, Vtw, btab, out);
}

// Round 4
// 174.668 us; speedup vs baseline: 1.5867x; 1.2409x over previous
//
#include <hip/hip_runtime.h>
#include <hip/hip_bf16.h>
#include <stdint.h>

typedef unsigned short u16;
typedef __attribute__((ext_vector_type(4))) float f32x4;
typedef __attribute__((ext_vector_type(8))) short s16x8;
typedef __attribute__((ext_vector_type(4))) float fvec4;

#define NH 12
#define DH 64
#define HID 768
#define SEQ 197
#define SP 208            // padded seq rows for Q/K slabs
#define VP 224            // padded seq cols for Vt slab
#define NREL 732
#define BATCH 64
#define MROWS (BATCH*SEQ) // 12608
#define NCAT (3*HID)      // 2304
#define BK 64
#define MT 99             // grid tiles in M (99*128 = 12672 >= 12608)
#define NT 18             // grid tiles in N (18*128 = 2304)
#define NWG (MT*NT)       // 1782

static __device__ __forceinline__ u16 f2bf(float f) {
  union { float f; uint32_t u; } v; v.f = f;
  uint32_t u = v.u;
  return (u16)((u + 0x7FFFu + ((u >> 16) & 1u)) >> 16);
}

// ---------------- prep: hidden fp32 -> bf16 ----------------
__global__ __launch_bounds__(256) void conv_x(const float* __restrict__ x, u16* __restrict__ xb, int n8) {
  int i = blockIdx.x * 256 + threadIdx.x;
  if (i >= n8) return;
  fvec4 a = ((const fvec4*)x)[2 * i];
  fvec4 b = ((const fvec4*)x)[2 * i + 1];
  s16x8 r;
  r[0] = (short)f2bf(a[0]); r[1] = (short)f2bf(a[1]); r[2] = (short)f2bf(a[2]); r[3] = (short)f2bf(a[3]);
  r[4] = (short)f2bf(b[0]); r[5] = (short)f2bf(b[1]); r[6] = (short)f2bf(b[2]); r[7] = (short)f2bf(b[3]);
  ((s16x8*)xb)[i] = r;
}

// ---------------- prep: W's -> transposed concat bf16 [NCAT][HID] ----------------
__global__ __launch_bounds__(256) void conv_w(const float* __restrict__ Wq, const float* __restrict__ Wk,
                                              const float* __restrict__ Wv, u16* __restrict__ Wt) {
  __shared__ float t[64][65];
  int n0 = blockIdx.x * 64;  // output row block (0..2303)
  int k0 = blockIdx.y * 64;  // k block (0..767)
  int m = n0 / HID;
  const float* W = (m == 0) ? Wq : ((m == 1) ? Wk : Wv);
  int nn0 = n0 - m * HID;
  for (int i = threadIdx.x; i < 64 * 64; i += 256) {
    int r = i >> 6, c = i & 63;
    t[r][c] = W[(size_t)(k0 + r) * HID + nn0 + c];   // coalesced read
  }
  __syncthreads();
  for (int i = threadIdx.x; i < 64 * 64; i += 256) {
    int r = i >> 6, c = i & 63;
    Wt[(size_t)(n0 + r) * HID + k0 + c] = f2bf(t[c][r]);  // coalesced write
  }
}

// ---------------- prep: bias concat (bq, 0, bv) ----------------
__global__ __launch_bounds__(256) void conv_b(const float* __restrict__ bq, const float* __restrict__ bv,
                                              float* __restrict__ bc) {
  int i = blockIdx.x * 256 + threadIdx.x;
  if (i < NCAT) {
    int m = i / HID, r = i - m * HID;
    bc[i] = (m == 0) ? bq[r] : ((m == 2) ? bv[r] : 0.f);
  }
}

// ---------------- prep: expand rel-pos bias to dense [NH][208][208] f32 ----------------
// Masked k-columns (k>=197) carry -1e30 => softmax mask comes free in attn.
__global__ __launch_bounds__(256) void expand_bias(const float* __restrict__ bias_table, float* __restrict__ Bx) {
  int i = blockIdx.x * 256 + threadIdx.x;
  if (i >= NH * 208 * 208) return;
  int h = i / (208 * 208);
  int r = i - h * 208 * 208;
  int q = r / 208, k = r - q * 208;
  float v;
  if (k >= SEQ) v = -1e30f;       // mask padded k
  else if (q >= SEQ) v = 0.f;     // padded q rows: unused
  else {
    int idx;
    if (q == 0) idx = (k == 0) ? 731 : 729;
    else if (k == 0) idx = 730;
    else {
      int iq = (q - 1) / 14, jq = (q - 1) % 14;
      int ik = (k - 1) / 14, jk = (k - 1) % 14;
      idx = (iq - ik + 13) * 27 + (jq - jk + 13);
    }
    v = bias_table[(size_t)idx * NH + h];
  }
  Bx[i] = v;
}

// ---------------- fused QKV GEMM: [12608x768]x[768x2304], bf16 MFMA ----------------
// 128x128 tile, BK=64, 4 waves (2x2), single 32 KiB LDS buffer, 2 barriers/K-step,
// 3 blocks/CU co-resident. XOR-swizzled LDS via inverse-swizzled global source.
// XCD-aware bijective swizzle (m204).

static __device__ __forceinline__ void stage128(const u16* __restrict__ gbase, int grow0, int growmax,
                                                u16* lds, int w, int l) {
#pragma unroll
  for (int i = 0; i < 4; ++i) {
    int ch = w * 4 + i;                    // wave-uniform 0..15
    int r = ch * 8 + (l >> 3);
    int grow = grow0 + r; if (grow > growmax) grow = growmax;
    int c = (l & 7) ^ (l >> 3);            // inverse swizzle on source
    const u16* g = gbase + (size_t)grow * HID + c * 8;
    __builtin_amdgcn_global_load_lds((const __attribute__((address_space(1))) void*)g,
                                     (__attribute__((address_space(3))) void*)(lds + ch * 512),
                                     16, 0, 0);
  }
}

__global__ __launch_bounds__(256, 3) void qkv_gemm(const u16* __restrict__ Xb, const u16* __restrict__ Wt,
                                                   const float* __restrict__ bc, u16* __restrict__ Qw,
                                                   u16* __restrict__ Kw, u16* __restrict__ Vtw) {
  __shared__ u16 As[128 * BK];
  __shared__ u16 Bs[128 * BK];
  const int tid = threadIdx.x;
  const int w = tid >> 6, l = tid & 63;
  const int wr = w >> 1, wc = w & 1;        // 2x2 wave grid, 64x64 per wave
  const int lg = l >> 4, li = l & 15;

  // bijective XCD chunking (m204): nwg=1782, q=222, r=6
  const int lin = blockIdx.x;
  const int xcd = lin & 7;
  const int pos = lin >> 3;
  const int work = (xcd < 6 ? xcd * 223 : 6 * 223 + (xcd - 6) * 222) + pos;
  const int mt = work / NT, nt = work - mt * NT;
  const int arow0 = mt * 128, brow0 = nt * 128;

  f32x4 acc[4][4] = {};

  for (int kt = 0; kt < 12; ++kt) {
    __syncthreads();                        // previous compute done before overwrite
    stage128(Xb + kt * BK, arow0, MROWS - 1, As, w, l);
    stage128(Wt + kt * BK, brow0, NCAT - 1, Bs, w, l);
    __syncthreads();                        // drain vmcnt; tile visible
#pragma unroll
    for (int kk = 0; kk < 2; ++kk) {
      s16x8 af[4], bf[4];
#pragma unroll
      for (int mi = 0; mi < 4; ++mi) {
        int r = wr * 64 + mi * 16 + li;
        int c = (kk * 4 + lg) ^ (r & 7);
        af[mi] = *(const s16x8*)((const char*)As + r * 128 + c * 16);
      }
#pragma unroll
      for (int ni = 0; ni < 4; ++ni) {
        int r = wc * 64 + ni * 16 + li;
        int c = (kk * 4 + lg) ^ (r & 7);
        bf[ni] = *(const s16x8*)((const char*)Bs + r * 128 + c * 16);
      }
#pragma unroll
      for (int mi = 0; mi < 4; ++mi)
#pragma unroll
        for (int ni = 0; ni < 4; ++ni)
          acc[mi][ni] = __builtin_amdgcn_mfma_f32_16x16x32_bf16(af[mi], bf[ni], acc[mi][ni], 0, 0, 0);
    }
  }

  // epilogue: bias, q-scale, scatter to Q/K/Vt (wave-uniform per-ni branch)
  int mv[4], hv[4], dv0[4]; float bcv[4];
#pragma unroll
  for (int ni = 0; ni < 4; ++ni) {
    int col = brow0 + wc * 64 + ni * 16 + li;
    int m = col / HID;
    int c7 = col - m * HID;
    mv[ni] = m; hv[ni] = c7 >> 6; dv0[ni] = c7 & 63;
    bcv[ni] = bc[col];
  }
#pragma unroll
  for (int mi = 0; mi < 4; ++mi) {
#pragma unroll
    for (int j = 0; j < 4; ++j) {
      int row = arow0 + wr * 64 + mi * 16 + lg * 4 + j;
      if (row < MROWS) {
        int b = row / SEQ, s = row - b * SEQ;
#pragma unroll
        for (int ni = 0; ni < 4; ++ni) {
          float vv = acc[mi][ni][j] + bcv[ni];
          int bh = b * NH + hv[ni];
          if (mv[ni] == 0)      Qw[((size_t)bh * SP + s) * DH + dv0[ni]] = f2bf(vv * 0.125f);
          else if (mv[ni] == 1) Kw[((size_t)bh * SP + s) * DH + dv0[ni]] = f2bf(vv);
          else                  Vtw[((size_t)bh * DH + dv0[ni]) * VP + s] = f2bf(vv);
        }
      }
    }
  }
}

// ---------------- fused attention: 1 WAVE per (bh, qf) — zero barriers ----------------
// 9984 single-wave blocks. P is private to the wave; in-wave LDS ordering is
// handled by compiler waitcnts. Bias+mask via dense Bx table (no index math,
// no LDS gather). ~12 independent waves/CU hide each other's load latency.
__global__ __launch_bounds__(64, 3) void attn(const u16* __restrict__ Qw, const u16* __restrict__ Kw,
                                              const u16* __restrict__ Vtw, const float* __restrict__ Bx,
                                              float* __restrict__ out) {
  __shared__ u16 P[16 * 232];      // 16 q-rows x 208 k-cols (+pad), 232 stride: conflict-free b128
  const int l = threadIdx.x;
  const int lg = l >> 4, li = l & 15;
  const int blk = blockIdx.x;      // bh * 13 + qf
  const int bh = blk / 13, qf = blk - bh * 13;
  const int b = bh / NH, h = bh - b * NH;

  // zero tail cols 208..231 (read by PV t-loop, never written)
  for (int t = l; t < 16 * 24; t += 64) {
    int rr = t / 24, cc = t - rr * 24;
    P[rr * 232 + 208 + cc] = 0;
  }

  const u16* Qb = Qw + (size_t)bh * SP * DH;
  const u16* Kb = Kw + (size_t)bh * SP * DH;
  const u16* Vb = Vtw + (size_t)bh * DH * VP;
  const float* Bh = Bx + ((size_t)h * 208 + qf * 16 + lg * 4) * 208;

  // ---- QK^T ----
  s16x8 a0 = *(const s16x8*)(Qb + (size_t)(qf * 16 + li) * DH + lg * 8);
  s16x8 a1 = *(const s16x8*)(Qb + (size_t)(qf * 16 + li) * DH + 32 + lg * 8);
  f32x4 S[13];
#pragma unroll
  for (int kf = 0; kf < 13; ++kf) {
    s16x8 b0 = *(const s16x8*)(Kb + (size_t)(kf * 16 + li) * DH + lg * 8);
    s16x8 b1 = *(const s16x8*)(Kb + (size_t)(kf * 16 + li) * DH + 32 + lg * 8);
    f32x4 c = {};
    c = __builtin_amdgcn_mfma_f32_16x16x32_bf16(a0, b0, c, 0, 0, 0);
    c = __builtin_amdgcn_mfma_f32_16x16x32_bf16(a1, b1, c, 0, 0, 0);
    S[kf] = c;
  }

  // ---- + bias (mask baked in) ----
#pragma unroll
  for (int kf = 0; kf < 13; ++kf)
#pragma unroll
    for (int j = 0; j < 4; ++j)
      S[kf][j] += Bh[j * 208 + kf * 16 + li];

  // ---- softmax over 13 regs x 16 lanes (per 16-lane group) ----
  float rinv[4];
#pragma unroll
  for (int j = 0; j < 4; ++j) {
    float m = S[0][j];
#pragma unroll
    for (int kf = 1; kf < 13; ++kf) m = fmaxf(m, S[kf][j]);
    m = fmaxf(m, __shfl_xor(m, 1));
    m = fmaxf(m, __shfl_xor(m, 2));
    m = fmaxf(m, __shfl_xor(m, 4));
    m = fmaxf(m, __shfl_xor(m, 8));
    float sum = 0.f;
#pragma unroll
    for (int kf = 0; kf < 13; ++kf) {
      float p = __expf(S[kf][j] - m);
      S[kf][j] = p;
      sum += p;
    }
    sum += __shfl_xor(sum, 1);
    sum += __shfl_xor(sum, 2);
    sum += __shfl_xor(sum, 4);
    sum += __shfl_xor(sum, 8);
    rinv[j] = 1.0f / sum;
  }

  // ---- transpose P into LDS (bf16) ----
#pragma unroll
  for (int kf = 0; kf < 13; ++kf)
#pragma unroll
    for (int j = 0; j < 4; ++j)
      P[(lg * 4 + j) * 232 + kf * 16 + li] = f2bf(S[kf][j]);

  // ---- PV ----
#pragma unroll
  for (int nf = 0; nf < 4; ++nf) {
    f32x4 c = {};
#pragma unroll
    for (int t = 0; t < 7; ++t) {
      s16x8 pa = *(const s16x8*)(&P[li * 232 + t * 32 + lg * 8]);
      s16x8 vb = *(const s16x8*)(Vb + (size_t)(nf * 16 + li) * VP + t * 32 + lg * 8);
      c = __builtin_amdgcn_mfma_f32_16x16x32_bf16(pa, vb, c, 0, 0, 0);
    }
#pragma unroll
    for (int j = 0; j < 4; ++j) {
      int q = qf * 16 + lg * 4 + j;
      if (q < SEQ)
        out[((size_t)(b * SEQ + q)) * HID + h * DH + nf * 16 + li] = c[j] * rinv[j];
    }
  }
}

extern "C" void kernel_launch(void* const* d_in, const int* in_sizes, int n_in,
                              void* d_out, int out_size, void* d_ws, size_t ws_size,
                              hipStream_t stream) {
  const float* hidden = (const float*)d_in[0];
  const float* Wq = (const float*)d_in[1];
  const float* bq = (const float*)d_in[2];
  const float* Wk = (const float*)d_in[3];
  const float* Wv = (const float*)d_in[4];
  const float* bv = (const float*)d_in[5];
  const float* btab = (const float*)d_in[6];
  float* out = (float*)d_out;

  char* ws = (char*)d_ws;
  u16* Xb  = (u16*)(ws);                       // 12608*768*2      = 19,365,888
  u16* Wt  = (u16*)(ws + 19365888);            // 2304*768*2       =  3,538,944
  float* bc = (float*)(ws + 22904832);         // 2304*4           =      9,216
  u16* Qw  = (u16*)(ws + 22914048);            // 768*208*64*2     = 20,447,232
  u16* Kw  = (u16*)(ws + 43361280);            // 768*208*64*2     = 20,447,232
  u16* Vtw = (u16*)(ws + 63808512);            // 768*64*224*2     = 22,020,096 (end 85,828,608)
  float* Bx = (float*)(ws);                    // reuses Xb region AFTER qkv_gemm (12*208*208*4 = 2,076,672)

  conv_x<<<dim3(4728), dim3(256), 0, stream>>>(hidden, Xb, (MROWS * HID) / 8);
  conv_w<<<dim3(NCAT / 64, HID / 64), dim3(256), 0, stream>>>(Wq, Wk, Wv, Wt);
  conv_b<<<dim3(9), dim3(256), 0, stream>>>(bq, bv, bc);
  qkv_gemm<<<dim3(NWG), dim3(256), 0, stream>>>(Xb, Wt, bc, Qw, Kw, Vtw);
  expand_bias<<<dim3((NH * 208 * 208 + 255) / 256), dim3(256), 0, stream>>>(btab, Bx);
  attn<<<dim3(768 * 13), dim3(64), 0, stream>>>(Qw, Kw, Vtw, Bx, out);
}